// Round 9
// baseline (386.374 us; speedup 1.0000x reference)
//
#include <hip/hip_runtime.h>

// LSTM decoder: B=1024, H=16, 4H=64 gates, T=128 steps x 16 cells = 2048
// strictly-serial cell evaluations per batch chain.
//
// Round-9 = round-8 with the h2_t type fixed to __fp16 ext_vector (what
// __builtin_amdgcn_cvt_pkrtz returns / __builtin_amdgcn_fdot2 takes).
//
// Mapping: one wave per chain (1024 waves = 1/SIMD). ZERO LDS ops in the
// main loop. Each lane kp=j&15 computes ALL FOUR gates of its hidden index
// locally (no i/f/g/o exchange -- round 7 measured the 4-bpermute exchange
// at ~100 exposed cyc/cell), using v_dot2_f32_f16:
//   - P = (h[kp], h[kp+/-1]) packed 2xf16, built with 1 DPP + 1 cvt_pkrtz
//   - 7 DPP row_ror rotations of the PACKED reg give all 8 h-pairs
//   - 4 gates x 8 fdot2 (f16 mul, f32 acc) = 32 inst vs 64 scalar FMA
// Weights pre-scaled (-log2e; -2log2e for g) and pre-permuted per lane
// (DPP direction probed at runtime), pre-converted to packed f16 at init.
// Calibrated model: wall/cell ~= inst*3.4 + 55 (no-LDS exposure floor).

#define B_ 1024
#define A_ 16
#define T_ 128
#define R_ 128
#define H_ 16

typedef __fp16 h2_t __attribute__((ext_vector_type(2)));

template<int CTRL>
__device__ __forceinline__ float dpp_rotf(float v) {
    return __int_as_float(__builtin_amdgcn_update_dpp(
        0, __float_as_int(v), CTRL, 0xF, 0xF, true));
}
template<int CTRL>
__device__ __forceinline__ h2_t dpp_roth(h2_t v) {
    int vi;
    __builtin_memcpy(&vi, &v, 4);
    int r = __builtin_amdgcn_update_dpp(0, vi, CTRL, 0xF, 0xF, true);
    h2_t o;
    __builtin_memcpy(&o, &r, 4);
    return o;
}

__global__ __launch_bounds__(64) void lstm_decoder_kernel(
    const float* __restrict__ y,     // (B,16)
    const float* __restrict__ u,     // (B,128)
    const float* __restrict__ W_ih,  // (64,1)
    const float* __restrict__ W_hh,  // (64,16)
    const float* __restrict__ b_ih,  // (64)
    const float* __restrict__ b_hh,  // (64)
    const float* __restrict__ W_lin, // (1,16)
    const float* __restrict__ b_lin, // (1)
    const float* __restrict__ W_h0,  // (16,128)
    const float* __restrict__ b_h0,  // (16)
    const float* __restrict__ W_c0,  // (16,128)
    const float* __restrict__ b_c0,  // (16)
    float* __restrict__ out)         // (B,144)
{
    const int b  = blockIdx.x;    // batch chain
    const int j  = threadIdx.x;   // lane 0..63
    const int kp = j & 15;        // hidden index this lane owns (4 row copies)

    __shared__ float lds_u[R_];
    __shared__ float lds_h[H_];
    __shared__ float lds_c[H_];

    // ---- stage u[b,:] to LDS (coalesced) ----
    lds_u[j]      = u[b * R_ + j];
    lds_u[j + 64] = u[b * R_ + j + 64];
    __syncthreads();

    // ---- h0 / c0 init: lanes 0..15 -> h0[kp], lanes 16..31 -> c0[kp] ----
    if (j < 32) {
        const float* Wr = (j < 16) ? (W_h0 + kp * R_) : (W_c0 + kp * R_);
        float acc = (j < 16) ? b_h0[kp] : b_c0[kp];
        #pragma unroll
        for (int r = 0; r < R_; r += 4) {
            float4 wv = *(const float4*)(Wr + r);
            float4 uv = *(const float4*)(&lds_u[r]);
            acc = fmaf(wv.x, uv.x, acc);
            acc = fmaf(wv.y, uv.y, acc);
            acc = fmaf(wv.z, uv.z, acc);
            acc = fmaf(wv.w, uv.w, acc);
        }
        if (j < 16) lds_h[kp] = acc;
        else        lds_c[kp] = acc;
    }

    // ---- probe DPP row_ror direction (no convention bet) ----
    // After ror:1, does lane kp hold (kp+1)&15 or (kp-1)&15 ?
    const int probe = __builtin_amdgcn_update_dpp(0, kp, 0x121, 0xF, 0xF, true);
    const bool plus = (probe == ((kp + 1) & 15));

    // ---- per-lane pre-scaled, pre-permuted, pre-packed f16 weights ----
    // Pair r2 of gate q multiplies P_rot(2*r2) = (h[idx(2r2)], h[idx(2r2+1)])
    // where idx(r) = (kp +/- r)&15 per probed direction.
    const float LOG2E = 1.4426950408889634f;
    h2_t wpk[4][8];      // 4 gates x 8 pairs (packed f16)
    h2_t wlpk[8];        // W_lin pairs (unscaled)
    float b4[4], wi4[4];
    #pragma unroll
    for (int q = 0; q < 4; ++q) {
        const float s = (q == 2) ? (-2.0f * LOG2E) : (-LOG2E);
        const int row = kp + 16 * q;
        b4[q]  = s * (b_ih[row] + b_hh[row]);
        wi4[q] = s * W_ih[row];
        #pragma unroll
        for (int r2 = 0; r2 < 8; ++r2) {
            const int i0 = plus ? ((kp + 2 * r2)     & 15) : ((kp - 2 * r2)     & 15);
            const int i1 = plus ? ((kp + 2 * r2 + 1) & 15) : ((kp - 2 * r2 - 1) & 15);
            wpk[q][r2] = __builtin_amdgcn_cvt_pkrtz(s * W_hh[row * H_ + i0],
                                                    s * W_hh[row * H_ + i1]);
        }
    }
    #pragma unroll
    for (int r2 = 0; r2 < 8; ++r2) {
        const int i0 = plus ? ((kp + 2 * r2)     & 15) : ((kp - 2 * r2)     & 15);
        const int i1 = plus ? ((kp + 2 * r2 + 1) & 15) : ((kp - 2 * r2 - 1) & 15);
        wlpk[r2] = __builtin_amdgcn_cvt_pkrtz(W_lin[i0], W_lin[i1]);
    }
    const float cK = -2.0f * LOG2E;   // for tanh(c)
    const float bl = b_lin[0];

    __syncthreads();
    float hk = lds_h[kp];     // h[kp], replicated across the 4 rows
    float c  = lds_c[kp];     // c[kp]

    float win[A_];
    #pragma unroll
    for (int t = 0; t < A_; ++t) win[t] = y[b * A_ + t];

    float pout0 = 0.f, pout1 = 0.f;

    for (int s = 0; s < T_; ++s) {
        #pragma unroll
        for (int t = 0; t < A_; ++t) {
            const float x = win[t];
            // ---- build packed h-pairs: P[r2] = (h[idx(2r2)], h[idx(2r2+1)])
            const float hn = dpp_rotf<0x121>(hk);
            const h2_t P0 = __builtin_amdgcn_cvt_pkrtz(hk, hn);
            const h2_t P1 = dpp_roth<0x122>(P0);
            const h2_t P2 = dpp_roth<0x124>(P0);
            const h2_t P3 = dpp_roth<0x126>(P0);
            const h2_t P4 = dpp_roth<0x128>(P0);
            const h2_t P5 = dpp_roth<0x12A>(P0);
            const h2_t P6 = dpp_roth<0x12C>(P0);
            const h2_t P7 = dpp_roth<0x12E>(P0);

            // ---- 4 gate dots: 8 fdot2 each, 2 acc chains per gate ----
            float zA[4], zB[4];
            #pragma unroll
            for (int q = 0; q < 4; ++q) {
                float a = fmaf(x, wi4[q], b4[q]);
                float d = 0.0f;
                a = __builtin_amdgcn_fdot2(P0, wpk[q][0], a, false);
                d = __builtin_amdgcn_fdot2(P1, wpk[q][1], d, false);
                a = __builtin_amdgcn_fdot2(P2, wpk[q][2], a, false);
                d = __builtin_amdgcn_fdot2(P3, wpk[q][3], d, false);
                a = __builtin_amdgcn_fdot2(P4, wpk[q][4], a, false);
                d = __builtin_amdgcn_fdot2(P5, wpk[q][5], d, false);
                a = __builtin_amdgcn_fdot2(P6, wpk[q][6], a, false);
                d = __builtin_amdgcn_fdot2(P7, wpk[q][7], d, false);
                zA[q] = a; zB[q] = d;
            }
            const float zi = zA[0] + zB[0];
            const float zf = zA[1] + zB[1];
            const float zg = zA[2] + zB[2];
            const float zo = zA[3] + zB[3];

            // ---- activations (pre-scaled: exp2 -> e^{-z} / e^{-2z}) ----
            const float iv = __builtin_amdgcn_rcpf(1.0f + __builtin_amdgcn_exp2f(zi));
            const float fv = __builtin_amdgcn_rcpf(1.0f + __builtin_amdgcn_exp2f(zf));
            const float gg = fmaf(2.0f, __builtin_amdgcn_rcpf(1.0f + __builtin_amdgcn_exp2f(zg)), -1.0f);
            const float ov = __builtin_amdgcn_rcpf(1.0f + __builtin_amdgcn_exp2f(zo));

            // ---- c, h[kp] update (all local, no cross-lane traffic) ----
            c = fmaf(fv, c, iv * gg);
            const float ec = __builtin_amdgcn_exp2f(cK * c);                       // e^{-2c}
            const float th = fmaf(2.0f, __builtin_amdgcn_rcpf(1.0f + ec), -1.0f);  // tanh(c)
            hk = ov * th;
        }

        // ---- pred = h . W_lin + b_lin (same packed-pair gather) ----
        {
            const float hn = dpp_rotf<0x121>(hk);
            const h2_t Q0 = __builtin_amdgcn_cvt_pkrtz(hk, hn);
            const h2_t Q1 = dpp_roth<0x122>(Q0);
            const h2_t Q2 = dpp_roth<0x124>(Q0);
            const h2_t Q3 = dpp_roth<0x126>(Q0);
            const h2_t Q4 = dpp_roth<0x128>(Q0);
            const h2_t Q5 = dpp_roth<0x12A>(Q0);
            const h2_t Q6 = dpp_roth<0x12C>(Q0);
            const h2_t Q7 = dpp_roth<0x12E>(Q0);
            float pa = bl, pb = 0.0f;
            pa = __builtin_amdgcn_fdot2(Q0, wlpk[0], pa, false);
            pb = __builtin_amdgcn_fdot2(Q1, wlpk[1], pb, false);
            pa = __builtin_amdgcn_fdot2(Q2, wlpk[2], pa, false);
            pb = __builtin_amdgcn_fdot2(Q3, wlpk[3], pb, false);
            pa = __builtin_amdgcn_fdot2(Q4, wlpk[4], pa, false);
            pb = __builtin_amdgcn_fdot2(Q5, wlpk[5], pb, false);
            pa = __builtin_amdgcn_fdot2(Q6, wlpk[6], pa, false);
            pb = __builtin_amdgcn_fdot2(Q7, wlpk[7], pb, false);
            const float p = pa + pb;

            // ---- window slide + pred stash ----
            #pragma unroll
            for (int t = 0; t < A_ - 1; ++t) win[t] = win[t + 1];
            win[A_ - 1] = p;
            if (s == j)      pout0 = p;
            if (s == j + 64) pout1 = p;
        }
    }

    // ---- output: out[b,0:16]=y[b,:], out[b,16+s]=pred_s ----
    if (j < A_) out[b * (A_ + T_) + j] = y[b * A_ + j];
    out[b * (A_ + T_) + A_ + j]      = pout0;
    out[b * (A_ + T_) + A_ + 64 + j] = pout1;
}

extern "C" void kernel_launch(void* const* d_in, const int* in_sizes, int n_in,
                              void* d_out, int out_size, void* d_ws, size_t ws_size,
                              hipStream_t stream) {
    const float* y     = (const float*)d_in[0];
    const float* u     = (const float*)d_in[1];
    const float* W_ih  = (const float*)d_in[2];
    const float* W_hh  = (const float*)d_in[3];
    const float* b_ih  = (const float*)d_in[4];
    const float* b_hh  = (const float*)d_in[5];
    const float* W_lin = (const float*)d_in[6];
    const float* b_lin = (const float*)d_in[7];
    const float* W_h0  = (const float*)d_in[8];
    const float* b_h0  = (const float*)d_in[9];
    const float* W_c0  = (const float*)d_in[10];
    const float* b_c0  = (const float*)d_in[11];
    float* out = (float*)d_out;

    lstm_decoder_kernel<<<B_, 64, 0, stream>>>(
        y, u, W_ih, W_hh, b_ih, b_hh, W_lin, b_lin,
        W_h0, b_h0, W_c0, b_c0, out);
}

// Round 10
// 377.093 us; speedup vs baseline: 1.0246x; 1.0246x over previous
//
#include <hip/hip_runtime.h>

// LSTM decoder: B=1024, H=16, 4H=64 gates, T=128 steps x 16 cells = 2048
// strictly-serial cell evaluations per batch chain.
//
// Round-10 "quad layout": one wave per chain (1024 waves = 1/SIMD).
//   lane j: kp = j>>2 (hidden index), q = j&3 (gate type i/f/g/o)
//   -> the FOUR GATES of hidden kp live in one DPP QUAD, so the i/f/g/o
//      exchange is 4 quad_perm DPP ops (pure VALU) instead of round-7's
//      4 ds_bpermute (~100 cyc exposed RT).
//   -> h[0..15] lives in LDS; each cell: 1 ds_write (replicated, conflict-
//      free) + 4 broadcast ds_read_b128. This is the single LDS RT per cell
//      (irreducible: h must cross 16-lane DPP rows somewhere).
//   -> dot consumes h in ABSOLUTE order (no per-lane weight permutation),
//      17 scalar v_fma_f32 (round 9 proved dot2/packed are half-rate; the
//      2-cyc scalar FMA is the densest issue on gfx950).
//   -> pred + window slide folded into cell 0 of the NEXT step (uses that
//      cell's h-read; pred_s is only consumed by cell 15 of step s+1).
// All f32 (absmax ~2.4e-4). Activation scaling (-log2e; -2log2e for g)
// folded into weights; tanh(c) = 2*rcp(1+e^{-2c}) - 1 (R3-bug orientation).

#define B_ 1024
#define A_ 16
#define T_ 128
#define R_ 128
#define H_ 16

template<int CTRL>
__device__ __forceinline__ float dpp_qpermf(float v) {
    return __int_as_float(__builtin_amdgcn_update_dpp(
        0, __float_as_int(v), CTRL, 0xF, 0xF, true));
}

__global__ __launch_bounds__(64) void lstm_decoder_kernel(
    const float* __restrict__ y,     // (B,16)
    const float* __restrict__ u,     // (B,128)
    const float* __restrict__ W_ih,  // (64,1)
    const float* __restrict__ W_hh,  // (64,16)
    const float* __restrict__ b_ih,  // (64)
    const float* __restrict__ b_hh,  // (64)
    const float* __restrict__ W_lin, // (1,16)
    const float* __restrict__ b_lin, // (1)
    const float* __restrict__ W_h0,  // (16,128)
    const float* __restrict__ b_h0,  // (16)
    const float* __restrict__ W_c0,  // (16,128)
    const float* __restrict__ b_c0,  // (16)
    float* __restrict__ out)         // (B,144)
{
    const int b  = blockIdx.x;    // batch chain
    const int j  = threadIdx.x;   // lane 0..63
    const int q  = j & 3;         // gate type: 0=i, 1=f, 2=g, 3=o
    const int kp = j >> 2;        // hidden index 0..15

    __shared__ float lds_u[R_];
    __shared__ __attribute__((aligned(16))) float lds_h4[4][H_]; // copy 0 is live
    __shared__ float lds_c[H_];

    // ---- stage u[b,:] to LDS (coalesced) ----
    lds_u[j]      = u[b * R_ + j];
    lds_u[j + 64] = u[b * R_ + j + 64];
    __syncthreads();

    // ---- h0 / c0 init: lanes 0..15 -> h0[k], lanes 16..31 -> c0[k] ----
    if (j < 32) {
        const int k16 = j & 15;
        const float* Wr = (j < 16) ? (W_h0 + k16 * R_) : (W_c0 + k16 * R_);
        float acc = (j < 16) ? b_h0[k16] : b_c0[k16];
        #pragma unroll
        for (int r = 0; r < R_; r += 4) {
            float4 wv = *(const float4*)(Wr + r);
            float4 uv = *(const float4*)(&lds_u[r]);
            acc = fmaf(wv.x, uv.x, acc);
            acc = fmaf(wv.y, uv.y, acc);
            acc = fmaf(wv.z, uv.z, acc);
            acc = fmaf(wv.w, uv.w, acc);
        }
        if (j < 16) lds_h4[0][k16] = acc;
        else        lds_c[k16] = acc;
    }
    __syncthreads();

    // ---- per-lane weights for gate row (16q + kp), ABSOLUTE k order ----
    const float LOG2E = 1.4426950408889634f;
    const float sq   = (q == 2) ? (-2.0f * LOG2E) : (-LOG2E);
    const int   grow = 16 * q + kp;
    float w[H_];
    {
        const float4 r0 = *(const float4*)(W_hh + grow * H_ + 0);
        const float4 r1 = *(const float4*)(W_hh + grow * H_ + 4);
        const float4 r2 = *(const float4*)(W_hh + grow * H_ + 8);
        const float4 r3 = *(const float4*)(W_hh + grow * H_ + 12);
        w[0]=sq*r0.x;  w[1]=sq*r0.y;  w[2]=sq*r0.z;  w[3]=sq*r0.w;
        w[4]=sq*r1.x;  w[5]=sq*r1.y;  w[6]=sq*r1.z;  w[7]=sq*r1.w;
        w[8]=sq*r2.x;  w[9]=sq*r2.y;  w[10]=sq*r2.z; w[11]=sq*r2.w;
        w[12]=sq*r3.x; w[13]=sq*r3.y; w[14]=sq*r3.z; w[15]=sq*r3.w;
    }
    const float bj   = sq * (b_ih[grow] + b_hh[grow]);
    const float wij  = sq * W_ih[grow];
    const float aAct = (q == 2) ? 2.0f : 1.0f;   // act = aAct*sigma + bAct
    const float bAct = (q == 2) ? -1.0f : 0.0f;
    const float cK   = -2.0f * LOG2E;            // for tanh(c)

    float wl[H_];
    #pragma unroll
    for (int m = 0; m < H_; ++m) wl[m] = W_lin[m];
    const float bl = b_lin[0];

    float c = lds_c[kp];

    float win[A_];
    #pragma unroll
    for (int t = 0; t < A_; ++t) win[t] = y[b * A_ + t];

    float pout0 = 0.f, pout1 = 0.f;

    for (int s = 0; s < T_; ++s) {
        #pragma unroll
        for (int t = 0; t < A_; ++t) {
            // ---- read h (broadcast, conflict-free); RT of the cell ----
            __builtin_amdgcn_wave_barrier();
            const float4 H0 = *(const float4*)&lds_h4[0][0];
            const float4 H1 = *(const float4*)&lds_h4[0][4];
            const float4 H2 = *(const float4*)&lds_h4[0][8];
            const float4 H3 = *(const float4*)&lds_h4[0][12];

            if (t == 0 && s > 0) {
                // pred_{s-1} from h at end of step s-1 (this read); slide.
                float pa = fmaf(H0.x, wl[0], bl);
                float pb = H0.y * wl[1];
                pa = fmaf(H0.z, wl[2], pa);  pb = fmaf(H0.w, wl[3], pb);
                pa = fmaf(H1.x, wl[4], pa);  pb = fmaf(H1.y, wl[5], pb);
                pa = fmaf(H1.z, wl[6], pa);  pb = fmaf(H1.w, wl[7], pb);
                pa = fmaf(H2.x, wl[8], pa);  pb = fmaf(H2.y, wl[9], pb);
                pa = fmaf(H2.z, wl[10], pa); pb = fmaf(H2.w, wl[11], pb);
                pa = fmaf(H3.x, wl[12], pa); pb = fmaf(H3.y, wl[13], pb);
                pa = fmaf(H3.z, wl[14], pa); pb = fmaf(H3.w, wl[15], pb);
                const float p = pa + pb;
                #pragma unroll
                for (int v = 0; v < A_ - 1; ++v) win[v] = win[v + 1];
                win[A_ - 1] = p;
                const int sp = s - 1;
                if (sp == j)      pout0 = p;
                if (sp == j + 64) pout1 = p;
            }

            const float x = win[t];
            // ---- one gate dot per lane, absolute order, 4 acc chains ----
            float z0 = fmaf(x, wij, bj);
            z0 = fmaf(H0.x, w[0], z0);
            float z1 = H0.y * w[1];
            float z2 = H0.z * w[2];
            float z3 = H0.w * w[3];
            z0 = fmaf(H1.x, w[4], z0);  z1 = fmaf(H1.y, w[5], z1);
            z2 = fmaf(H1.z, w[6], z2);  z3 = fmaf(H1.w, w[7], z3);
            z0 = fmaf(H2.x, w[8], z0);  z1 = fmaf(H2.y, w[9], z1);
            z2 = fmaf(H2.z, w[10], z2); z3 = fmaf(H2.w, w[11], z3);
            z0 = fmaf(H3.x, w[12], z0); z1 = fmaf(H3.y, w[13], z1);
            z2 = fmaf(H3.z, w[14], z2); z3 = fmaf(H3.w, w[15], z3);
            const float z = (z0 + z1) + (z2 + z3);

            // ---- own-gate activation (sigma; tanh for q==2 via aAct/bAct)
            const float e   = __builtin_amdgcn_exp2f(z);
            const float sg  = __builtin_amdgcn_rcpf(1.0f + e);
            const float act = fmaf(aAct, sg, bAct);

            // ---- i/f/g/o exchange: 4 quad_perm DPP (pure VALU, no LDS) ----
            const float iv = dpp_qpermf<0x00>(act);  // slot0 -> all
            const float fv = dpp_qpermf<0x55>(act);  // slot1 -> all
            const float gg = dpp_qpermf<0xAA>(act);  // slot2 -> all
            const float ov = dpp_qpermf<0xFF>(act);  // slot3 -> all

            // ---- c, tanh(c), h[kp] (redundant x4 within quad) ----
            c = fmaf(fv, c, iv * gg);
            const float ec = __builtin_amdgcn_exp2f(cK * c);                       // e^{-2c}
            const float th = fmaf(2.0f, __builtin_amdgcn_rcpf(1.0f + ec), -1.0f);  // tanh(c)
            const float hk = ov * th;

            // ---- publish h: every lane writes its quad's copy q (distinct
            //      words, <=2-way banked = free); readers use copy 0 ----
            __builtin_amdgcn_wave_barrier();
            lds_h4[q][kp] = hk;
        }
    }

    // ---- epilogue: pred_127 ----
    __builtin_amdgcn_wave_barrier();
    {
        const float4 H0 = *(const float4*)&lds_h4[0][0];
        const float4 H1 = *(const float4*)&lds_h4[0][4];
        const float4 H2 = *(const float4*)&lds_h4[0][8];
        const float4 H3 = *(const float4*)&lds_h4[0][12];
        float pa = fmaf(H0.x, wl[0], bl);
        float pb = H0.y * wl[1];
        pa = fmaf(H0.z, wl[2], pa);  pb = fmaf(H0.w, wl[3], pb);
        pa = fmaf(H1.x, wl[4], pa);  pb = fmaf(H1.y, wl[5], pb);
        pa = fmaf(H1.z, wl[6], pa);  pb = fmaf(H1.w, wl[7], pb);
        pa = fmaf(H2.x, wl[8], pa);  pb = fmaf(H2.y, wl[9], pb);
        pa = fmaf(H2.z, wl[10], pa); pb = fmaf(H2.w, wl[11], pb);
        pa = fmaf(H3.x, wl[12], pa); pb = fmaf(H3.y, wl[13], pb);
        pa = fmaf(H3.z, wl[14], pa); pb = fmaf(H3.w, wl[15], pb);
        const float p = pa + pb;
        if (127 == j)      pout0 = p;   // j<64, never taken for pout0... kept for clarity
        if (127 == j + 64) pout1 = p;   // lane 63 stashes pred_127
    }

    // ---- output: out[b,0:16]=y[b,:], out[b,16+s]=pred_s ----
    if (j < A_) out[b * (A_ + T_) + j] = y[b * A_ + j];
    out[b * (A_ + T_) + A_ + j]      = pout0;
    out[b * (A_ + T_) + A_ + 64 + j] = pout1;
}

extern "C" void kernel_launch(void* const* d_in, const int* in_sizes, int n_in,
                              void* d_out, int out_size, void* d_ws, size_t ws_size,
                              hipStream_t stream) {
    const float* y     = (const float*)d_in[0];
    const float* u     = (const float*)d_in[1];
    const float* W_ih  = (const float*)d_in[2];
    const float* W_hh  = (const float*)d_in[3];
    const float* b_ih  = (const float*)d_in[4];
    const float* b_hh  = (const float*)d_in[5];
    const float* W_lin = (const float*)d_in[6];
    const float* b_lin = (const float*)d_in[7];
    const float* W_h0  = (const float*)d_in[8];
    const float* b_h0  = (const float*)d_in[9];
    const float* W_c0  = (const float*)d_in[10];
    const float* b_c0  = (const float*)d_in[11];
    float* out = (float*)d_out;

    lstm_decoder_kernel<<<B_, 64, 0, stream>>>(
        y, u, W_ih, W_hh, b_ih, b_hh, W_lin, b_lin,
        W_h0, b_h0, W_c0, b_c0, out);
}

// Round 11
// 358.897 us; speedup vs baseline: 1.0766x; 1.0507x over previous
//
#include <hip/hip_runtime.h>

// LSTM decoder: B=1024, H=16, 4H=64 gates, T=128 steps x 16 cells = 2048
// strictly-serial cell evaluations per batch chain.
//
// Round-11 = round-7 (best: 291us kernel, 188 issue + 153 exposed cyc/cell)
// with three critical-path trims:
//  1. pred gather merged into cell t=0 of the next step (reuses that cell's
//     15 DPP rotations; deletes the separate per-step pred gather).
//  2. activation numerator FMA runs parallel to v_rcp:
//     act = fmaf(nA,e,nB) * rcp(1+e)   (nA,nB per-lane: sigmoid vs tanh)
//     hk  = fmaf(-ov,ec,ov) * rcp(1+ec)
//  3. dot written as z += hr*w to let LLVM fold v_mov_b32_dpp into v_fmac.
//
// Mapping (R7): one wave per chain (1024 waves = 1/SIMD). Lane j computes
// only its own gate j: 15 DPP row_ror ops broadcast h within each 16-lane
// row (weights per-lane pre-permuted, direction probed at runtime); ONE
// 4-bpermute exchange brings {i,f,g,o} to every lane (measured cheapest
// row-crossing: 153 exposed vs 225 for LDS write->read).

#define B_ 1024
#define A_ 16
#define T_ 128
#define R_ 128
#define H_ 16

template<int CTRL>
__device__ __forceinline__ float dpp_rotf(float v) {
    return __int_as_float(__builtin_amdgcn_update_dpp(
        0, __float_as_int(v), CTRL, 0xF, 0xF, true));
}

__global__ __launch_bounds__(64) void lstm_decoder_kernel(
    const float* __restrict__ y,     // (B,16)
    const float* __restrict__ u,     // (B,128)
    const float* __restrict__ W_ih,  // (64,1)
    const float* __restrict__ W_hh,  // (64,16)
    const float* __restrict__ b_ih,  // (64)
    const float* __restrict__ b_hh,  // (64)
    const float* __restrict__ W_lin, // (1,16)
    const float* __restrict__ b_lin, // (1)
    const float* __restrict__ W_h0,  // (16,128)
    const float* __restrict__ b_h0,  // (16)
    const float* __restrict__ W_c0,  // (16,128)
    const float* __restrict__ b_c0,  // (16)
    float* __restrict__ out)         // (B,144)
{
    const int b  = blockIdx.x;    // batch chain
    const int j  = threadIdx.x;   // lane = gate index 0..63
    const int kp = j & 15;        // hidden index this lane carries

    __shared__ float lds_u[R_];
    __shared__ float lds_h[H_];
    __shared__ float lds_c[H_];

    // ---- stage u[b,:] to LDS (coalesced) ----
    lds_u[j]      = u[b * R_ + j];
    lds_u[j + 64] = u[b * R_ + j + 64];
    __syncthreads();

    // ---- h0 / c0 init: lanes 0..15 -> h0[kp], lanes 16..31 -> c0[kp] ----
    if (j < 32) {
        const float* Wr = (j < 16) ? (W_h0 + kp * R_) : (W_c0 + kp * R_);
        float acc = (j < 16) ? b_h0[kp] : b_c0[kp];
        #pragma unroll
        for (int r = 0; r < R_; r += 4) {
            float4 wv = *(const float4*)(Wr + r);
            float4 uv = *(const float4*)(&lds_u[r]);
            acc = fmaf(wv.x, uv.x, acc);
            acc = fmaf(wv.y, uv.y, acc);
            acc = fmaf(wv.z, uv.z, acc);
            acc = fmaf(wv.w, uv.w, acc);
        }
        if (j < 16) lds_h[kp] = acc;
        else        lds_c[kp] = acc;
    }

    // ---- probe DPP row_ror direction (no convention bet) ----
    const int probe = __builtin_amdgcn_update_dpp(0, kp, 0x121, 0xF, 0xF, true);
    const bool plus = (probe == ((kp + 1) & 15));

    // ---- per-lane pre-scaled, pre-permuted weights for gate row j ----
    const float LOG2E = 1.4426950408889634f;
    const bool  isg   = ((j >> 4) == 2);           // rows 32..47 = g gate
    const float sj    = isg ? (-2.0f * LOG2E) : (-LOG2E);
    float w16[H_], wlr[H_];
    #pragma unroll
    for (int r = 0; r < H_; ++r) {
        const int idx = plus ? ((kp + r) & 15) : ((kp - r) & 15);
        w16[r] = sj * W_hh[j * H_ + idx];
        wlr[r] = W_lin[idx];
    }
    const float bj  = sj * (b_ih[j] + b_hh[j]);
    const float wij = sj * W_ih[j];
    // act = fmaf(nA, e, nB) * rcp(1+e):
    //   sigmoid rows: (0*e + 1)            * rcp = sigma(z_raw)
    //   g rows:       (-1*e + 1)           * rcp = tanh(z_raw)   (e = e^{-2z})
    const float nA = isg ? -1.0f : 0.0f;
    const float nB = 1.0f;
    const float cK = -2.0f * LOG2E;                // for tanh(c)
    const float bl = b_lin[0];

    __syncthreads();
    float hk = lds_h[kp];     // h[kp], replicated across the 4 rows
    float c  = lds_c[kp];     // c[kp]

    float win[A_];
    #pragma unroll
    for (int t = 0; t < A_; ++t) win[t] = y[b * A_ + t];

    float pout0 = 0.f, pout1 = 0.f;

    for (int s = 0; s < T_; ++s) {
        #pragma unroll
        for (int t = 0; t < A_; ++t) {
            // ---- 15 DPP rotations of hk (row all-gather) ----
            const float h1  = dpp_rotf<0x121>(hk);
            const float h2  = dpp_rotf<0x122>(hk);
            const float h3  = dpp_rotf<0x123>(hk);
            const float h4  = dpp_rotf<0x124>(hk);
            const float h5  = dpp_rotf<0x125>(hk);
            const float h6  = dpp_rotf<0x126>(hk);
            const float h7  = dpp_rotf<0x127>(hk);
            const float h8  = dpp_rotf<0x128>(hk);
            const float h9  = dpp_rotf<0x129>(hk);
            const float h10 = dpp_rotf<0x12A>(hk);
            const float h11 = dpp_rotf<0x12B>(hk);
            const float h12 = dpp_rotf<0x12C>(hk);
            const float h13 = dpp_rotf<0x12D>(hk);
            const float h14 = dpp_rotf<0x12E>(hk);
            const float h15 = dpp_rotf<0x12F>(hk);

            if (t == 0 && s > 0) {
                // pred_{s-1} = h.W_lin + b_lin, reusing this cell's gather
                float pa = fmaf(hk,  wlr[0],  bl);
                float pb = h1 * wlr[1];
                pa = fmaf(h2,  wlr[2],  pa);  pb = fmaf(h3,  wlr[3],  pb);
                pa = fmaf(h4,  wlr[4],  pa);  pb = fmaf(h5,  wlr[5],  pb);
                pa = fmaf(h6,  wlr[6],  pa);  pb = fmaf(h7,  wlr[7],  pb);
                pa = fmaf(h8,  wlr[8],  pa);  pb = fmaf(h9,  wlr[9],  pb);
                pa = fmaf(h10, wlr[10], pa);  pb = fmaf(h11, wlr[11], pb);
                pa = fmaf(h12, wlr[12], pa);  pb = fmaf(h13, wlr[13], pb);
                pa = fmaf(h14, wlr[14], pa);  pb = fmaf(h15, wlr[15], pb);
                const float p = pa + pb;
                #pragma unroll
                for (int v = 0; v < A_ - 1; ++v) win[v] = win[v + 1];
                win[A_ - 1] = p;
                const int sp = s - 1;
                if (sp == j)      pout0 = p;
                if (sp == j + 64) pout1 = p;
            }

            const float x = win[t];
            // ---- own-gate dot (fmac-friendly: z += hr*w), 4 acc chains ----
            float z0 = fmaf(x, wij, bj);
            z0 += hk * w16[0];
            float z1 = h1 * w16[1];
            float z2 = h2 * w16[2];
            float z3 = h3 * w16[3];
            z0 += h4  * w16[4];   z1 += h5  * w16[5];
            z2 += h6  * w16[6];   z3 += h7  * w16[7];
            z0 += h8  * w16[8];   z1 += h9  * w16[9];
            z2 += h10 * w16[10];  z3 += h11 * w16[11];
            z0 += h12 * w16[12];  z1 += h13 * w16[13];
            z2 += h14 * w16[14];  z3 += h15 * w16[15];
            const float z = (z0 + z1) + (z2 + z3);

            // ---- own-gate activation; numerator FMA overlaps rcp ----
            const float e    = __builtin_amdgcn_exp2f(z);
            const float rcpv = __builtin_amdgcn_rcpf(1.0f + e);
            const float num  = fmaf(nA, e, nB);
            const float act  = num * rcpv;

            // ---- 4-bpermute gate exchange (only row-crossing per cell) ----
            const float iv = __shfl(act, kp,      64);
            const float gg = __shfl(act, kp + 32, 64);
            const float fv = __shfl(act, kp + 16, 64);
            const float ov = __shfl(act, kp + 48, 64);

            // ---- c, h[kp] update; tanh numerator overlaps rcp ----
            c = fmaf(fv, c, iv * gg);
            const float ec = __builtin_amdgcn_exp2f(cK * c);        // e^{-2c}
            const float rc = __builtin_amdgcn_rcpf(1.0f + ec);
            const float nm = fmaf(-ov, ec, ov);                     // ov*(1-ec)
            hk = nm * rc;                                           // ov*tanh(c)
        }
    }

    // ---- epilogue: pred_127 (one more gather) ----
    {
        const float h1  = dpp_rotf<0x121>(hk);
        const float h2  = dpp_rotf<0x122>(hk);
        const float h3  = dpp_rotf<0x123>(hk);
        const float h4  = dpp_rotf<0x124>(hk);
        const float h5  = dpp_rotf<0x125>(hk);
        const float h6  = dpp_rotf<0x126>(hk);
        const float h7  = dpp_rotf<0x127>(hk);
        const float h8  = dpp_rotf<0x128>(hk);
        const float h9  = dpp_rotf<0x129>(hk);
        const float h10 = dpp_rotf<0x12A>(hk);
        const float h11 = dpp_rotf<0x12B>(hk);
        const float h12 = dpp_rotf<0x12C>(hk);
        const float h13 = dpp_rotf<0x12D>(hk);
        const float h14 = dpp_rotf<0x12E>(hk);
        const float h15 = dpp_rotf<0x12F>(hk);
        float pa = fmaf(hk,  wlr[0],  bl);
        float pb = h1 * wlr[1];
        pa = fmaf(h2,  wlr[2],  pa);  pb = fmaf(h3,  wlr[3],  pb);
        pa = fmaf(h4,  wlr[4],  pa);  pb = fmaf(h5,  wlr[5],  pb);
        pa = fmaf(h6,  wlr[6],  pa);  pb = fmaf(h7,  wlr[7],  pb);
        pa = fmaf(h8,  wlr[8],  pa);  pb = fmaf(h9,  wlr[9],  pb);
        pa = fmaf(h10, wlr[10], pa);  pb = fmaf(h11, wlr[11], pb);
        pa = fmaf(h12, wlr[12], pa);  pb = fmaf(h13, wlr[13], pb);
        pa = fmaf(h14, wlr[14], pa);  pb = fmaf(h15, wlr[15], pb);
        const float p = pa + pb;
        if (127 == j + 64) pout1 = p;   // lane 63 stashes pred_127
    }

    // ---- output: out[b,0:16]=y[b,:], out[b,16+s]=pred_s ----
    if (j < A_) out[b * (A_ + T_) + j] = y[b * A_ + j];
    out[b * (A_ + T_) + A_ + j]      = pout0;
    out[b * (A_ + T_) + A_ + 64 + j] = pout1;
}

extern "C" void kernel_launch(void* const* d_in, const int* in_sizes, int n_in,
                              void* d_out, int out_size, void* d_ws, size_t ws_size,
                              hipStream_t stream) {
    const float* y     = (const float*)d_in[0];
    const float* u     = (const float*)d_in[1];
    const float* W_ih  = (const float*)d_in[2];
    const float* W_hh  = (const float*)d_in[3];
    const float* b_ih  = (const float*)d_in[4];
    const float* b_hh  = (const float*)d_in[5];
    const float* W_lin = (const float*)d_in[6];
    const float* b_lin = (const float*)d_in[7];
    const float* W_h0  = (const float*)d_in[8];
    const float* b_h0  = (const float*)d_in[9];
    const float* W_c0  = (const float*)d_in[10];
    const float* b_c0  = (const float*)d_in[11];
    float* out = (float*)d_out;

    lstm_decoder_kernel<<<B_, 64, 0, stream>>>(
        y, u, W_ih, W_hh, b_ih, b_hh, W_lin, b_lin,
        W_h0, b_h0, W_c0, b_c0, out);
}

// Round 12
// 340.139 us; speedup vs baseline: 1.1359x; 1.0551x over previous
//
#include <hip/hip_runtime.h>

// LSTM decoder: B=1024, H=16, 4H=64 gates, T=128 steps x 16 cells = 2048
// strictly-serial cell evaluations per batch chain.
//
// Round-12 = exact round-7 structure (best measured: 291us kernel,
// 341 cyc/cell = 188 issue + ~120 LDS RT + ~33 trans residue) plus two
// zero-cost critical-path cuts (round 11 proved non-free trims regress):
//  1. c kept in exp2-scaled domain c' = -2*log2e * c. The scale is folded
//     into the i-row activation constant (aAct = cK; i-act is consumed only
//     as iv*gg), so the tail's cK*c multiply disappears for free.
//  2. tail tanh: hk = fmaf(-ov,ec,ov) * rcp(1+ec) -- numerator FMA runs
//     parallel to the rcp (path add->rcp->mul, one op shorter).
//
// Mapping (R7): one wave per chain (1024 waves = 1/SIMD). Lane j computes
// only its own gate j: 15 DPP row_ror ops broadcast h within each 16-lane
// row (weights per-lane pre-permuted, direction probed at runtime); ONE
// 4-bpermute exchange brings {i,f,g,o} to every lane (measured cheapest
// row-crossing: bpermute RT ~120 < LDS write->read RT ~225).

#define B_ 1024
#define A_ 16
#define T_ 128
#define R_ 128
#define H_ 16

template<int CTRL>
__device__ __forceinline__ float dpp_rotf(float v) {
    return __int_as_float(__builtin_amdgcn_update_dpp(
        0, __float_as_int(v), CTRL, 0xF, 0xF, true));
}

__global__ __launch_bounds__(64) void lstm_decoder_kernel(
    const float* __restrict__ y,     // (B,16)
    const float* __restrict__ u,     // (B,128)
    const float* __restrict__ W_ih,  // (64,1)
    const float* __restrict__ W_hh,  // (64,16)
    const float* __restrict__ b_ih,  // (64)
    const float* __restrict__ b_hh,  // (64)
    const float* __restrict__ W_lin, // (1,16)
    const float* __restrict__ b_lin, // (1)
    const float* __restrict__ W_h0,  // (16,128)
    const float* __restrict__ b_h0,  // (16)
    const float* __restrict__ W_c0,  // (16,128)
    const float* __restrict__ b_c0,  // (16)
    float* __restrict__ out)         // (B,144)
{
    const int b  = blockIdx.x;    // batch chain
    const int j  = threadIdx.x;   // lane = gate index 0..63
    const int kp = j & 15;        // hidden index this lane carries

    __shared__ float lds_u[R_];
    __shared__ float lds_h[H_];
    __shared__ float lds_c[H_];

    // ---- stage u[b,:] to LDS (coalesced) ----
    lds_u[j]      = u[b * R_ + j];
    lds_u[j + 64] = u[b * R_ + j + 64];
    __syncthreads();

    // ---- h0 / c0 init: lanes 0..15 -> h0[kp], lanes 16..31 -> c0[kp] ----
    if (j < 32) {
        const float* Wr = (j < 16) ? (W_h0 + kp * R_) : (W_c0 + kp * R_);
        float acc = (j < 16) ? b_h0[kp] : b_c0[kp];
        #pragma unroll
        for (int r = 0; r < R_; r += 4) {
            float4 wv = *(const float4*)(Wr + r);
            float4 uv = *(const float4*)(&lds_u[r]);
            acc = fmaf(wv.x, uv.x, acc);
            acc = fmaf(wv.y, uv.y, acc);
            acc = fmaf(wv.z, uv.z, acc);
            acc = fmaf(wv.w, uv.w, acc);
        }
        if (j < 16) lds_h[kp] = acc;
        else        lds_c[kp] = acc;
    }

    // ---- probe DPP row_ror direction (no convention bet) ----
    const int probe = __builtin_amdgcn_update_dpp(0, kp, 0x121, 0xF, 0xF, true);
    const bool plus = (probe == ((kp + 1) & 15));

    // ---- per-lane pre-scaled, pre-permuted weights for gate row j ----
    const float LOG2E = 1.4426950408889634f;
    const float cK    = -2.0f * LOG2E;           // tanh(c) exp2 scale
    const int   gsel  = (j >> 4);                // 0=i, 1=f, 2=g, 3=o
    const bool  isg   = (gsel == 2);
    const float sj    = isg ? (-2.0f * LOG2E) : (-LOG2E);
    float w16[H_], wlr[H_];
    #pragma unroll
    for (int r = 0; r < H_; ++r) {
        const int idx = plus ? ((kp + r) & 15) : ((kp - r) & 15);
        w16[r] = sj * W_hh[j * H_ + idx];
        wlr[r] = W_lin[idx];
    }
    const float bj  = sj * (b_ih[j] + b_hh[j]);
    const float wij = sj * W_ih[j];
    // act = fmaf(aAct, sigma, bAct):
    //   i rows:  cK * sigma       (pre-scales iv so c stays in cK domain)
    //   f,o rows: 1 * sigma
    //   g rows:  2 * sigma - 1  = tanh (e = e^{-2z} via sj)
    const float aAct = isg ? 2.0f : ((gsel == 0) ? cK : 1.0f);
    const float bAct = isg ? -1.0f : 0.0f;
    const float bl   = b_lin[0];

    __syncthreads();
    float hk = lds_h[kp];          // h[kp], replicated across the 4 rows
    float c  = cK * lds_c[kp];     // c in SCALED domain: c' = cK * c_nat

    float win[A_];
    #pragma unroll
    for (int t = 0; t < A_; ++t) win[t] = y[b * A_ + t];

    float pout0 = 0.f, pout1 = 0.f;

    for (int s = 0; s < T_; ++s) {
        #pragma unroll
        for (int t = 0; t < A_; ++t) {
            const float x = win[t];
            // ---- own-gate dot via DPP row all-gather (no LDS) ----
            float z0 = fmaf(x, wij, bj);
            z0 = fmaf(hk, w16[0], z0);
            float z1, z2, z3;
            { const float hr = dpp_rotf<0x121>(hk); z1 = hr * w16[1]; }
            { const float hr = dpp_rotf<0x122>(hk); z2 = hr * w16[2]; }
            { const float hr = dpp_rotf<0x123>(hk); z3 = hr * w16[3]; }
#define CELL_ROT(R, CTRL, ACC)                                        \
            { const float hr = dpp_rotf<CTRL>(hk);                    \
              ACC = fmaf(hr, w16[R], ACC); }
            CELL_ROT(4,  0x124, z0)
            CELL_ROT(5,  0x125, z1)
            CELL_ROT(6,  0x126, z2)
            CELL_ROT(7,  0x127, z3)
            CELL_ROT(8,  0x128, z0)
            CELL_ROT(9,  0x129, z1)
            CELL_ROT(10, 0x12A, z2)
            CELL_ROT(11, 0x12B, z3)
            CELL_ROT(12, 0x12C, z0)
            CELL_ROT(13, 0x12D, z1)
            CELL_ROT(14, 0x12E, z2)
            CELL_ROT(15, 0x12F, z3)
#undef CELL_ROT
            const float z = (z0 + z1) + (z2 + z3);

            // ---- own-gate activation ----
            const float e   = __builtin_amdgcn_exp2f(z);
            const float sg  = __builtin_amdgcn_rcpf(1.0f + e);
            const float act = fmaf(aAct, sg, bAct);

            // ---- 4-bpermute gate exchange (only row-crossing per cell) ----
            const float iv = __shfl(act, kp,      64);   // cK-scaled
            const float fv = __shfl(act, kp + 16, 64);
            const float gg = __shfl(act, kp + 32, 64);
            const float ov = __shfl(act, kp + 48, 64);

            // ---- c (scaled domain), tanh(c), h[kp] ----
            c = fmaf(fv, c, iv * gg);                    // c' = cK * c_nat
            const float ec = __builtin_amdgcn_exp2f(c);  // e^{-2 c_nat}
            const float rc = __builtin_amdgcn_rcpf(1.0f + ec);
            const float nm = fmaf(-ov, ec, ov);          // ov*(1-ec)
            hk = nm * rc;                                // ov*tanh(c_nat)
        }

        // ---- pred = h . W_lin + b_lin via one more DPP all-gather ----
        float pa = fmaf(hk, wlr[0], bl);
        float pb;
        { const float hr = dpp_rotf<0x121>(hk); pb = hr * wlr[1]; }
#define PRED_ROT(R, CTRL, ACC)                                        \
        { const float hr = dpp_rotf<CTRL>(hk);                        \
          ACC = fmaf(hr, wlr[R], ACC); }
        PRED_ROT(2,  0x122, pa)
        PRED_ROT(3,  0x123, pb)
        PRED_ROT(4,  0x124, pa)
        PRED_ROT(5,  0x125, pb)
        PRED_ROT(6,  0x126, pa)
        PRED_ROT(7,  0x127, pb)
        PRED_ROT(8,  0x128, pa)
        PRED_ROT(9,  0x129, pb)
        PRED_ROT(10, 0x12A, pa)
        PRED_ROT(11, 0x12B, pb)
        PRED_ROT(12, 0x12C, pa)
        PRED_ROT(13, 0x12D, pb)
        PRED_ROT(14, 0x12E, pa)
        PRED_ROT(15, 0x12F, pb)
#undef PRED_ROT
        const float p = pa + pb;

        // ---- window slide + pred stash ----
        #pragma unroll
        for (int t = 0; t < A_ - 1; ++t) win[t] = win[t + 1];
        win[A_ - 1] = p;
        if (s == j)      pout0 = p;
        if (s == j + 64) pout1 = p;
    }

    // ---- output: out[b,0:16]=y[b,:], out[b,16+s]=pred_s ----
    if (j < A_) out[b * (A_ + T_) + j] = y[b * A_ + j];
    out[b * (A_ + T_) + A_ + j]      = pout0;
    out[b * (A_ + T_) + A_ + 64 + j] = pout1;
}

extern "C" void kernel_launch(void* const* d_in, const int* in_sizes, int n_in,
                              void* d_out, int out_size, void* d_ws, size_t ws_size,
                              hipStream_t stream) {
    const float* y     = (const float*)d_in[0];
    const float* u     = (const float*)d_in[1];
    const float* W_ih  = (const float*)d_in[2];
    const float* W_hh  = (const float*)d_in[3];
    const float* b_ih  = (const float*)d_in[4];
    const float* b_hh  = (const float*)d_in[5];
    const float* W_lin = (const float*)d_in[6];
    const float* b_lin = (const float*)d_in[7];
    const float* W_h0  = (const float*)d_in[8];
    const float* b_h0  = (const float*)d_in[9];
    const float* W_c0  = (const float*)d_in[10];
    const float* b_c0  = (const float*)d_in[11];
    float* out = (float*)d_out;

    lstm_decoder_kernel<<<B_, 64, 0, stream>>>(
        y, u, W_ih, W_hh, b_ih, b_hh, W_lin, b_lin,
        W_h0, b_h0, W_c0, b_c0, out);
}

// Round 13
// 315.578 us; speedup vs baseline: 1.2243x; 1.0778x over previous
//
#include <hip/hip_runtime.h>

// LSTM decoder: B=1024, H=16, 4H=64 gates, T=128 steps x 16 cells = 2048
// strictly-serial cell evaluations per batch chain.
//
// Round-13 = round-12 (287us kernel = 337 cyc/cell: 181 issue + 156 exposed)
// with the 4-ds_bpermute gate exchange (~100-120 cyc exposed RT, the last
// big latency term) replaced by gfx950's cross-row VALU permutes:
//   A=act; (P,Q)=v_permlane32_swap(A,A); (R,S)=v_permlane16_swap(P,P);
//   (T,U)=v_permlane16_swap(Q,Q)  ->  R,S,T,U = the four gate rows each
// broadcast to all lanes, intra-row position (kp) preserved. 3 VALU ops,
// zero LDS. Slot->gate mapping is PROBED at init (feed row-id through the
// network) and neutralized by relabeling which gate each lane computes
// (per-lane weight loads make this free) -- correct under any row-permute
// semantics, including the __shfl fallback if the builtin is missing.
//
// Keeps R12's wins: c in exp2-scaled domain (cK folded into the i-gate's
// activation constant), tail tanh as fmaf(-ov,ec,ov)*rcp(1+ec), per-lane
// pre-permuted weights for the 15-DPP row all-gather of h.

#define B_ 1024
#define A_ 16
#define T_ 128
#define R_ 128
#define H_ 16

typedef unsigned int u32x2 __attribute__((ext_vector_type(2)));

template<int CTRL>
__device__ __forceinline__ float dpp_rotf(float v) {
    return __int_as_float(__builtin_amdgcn_update_dpp(
        0, __float_as_int(v), CTRL, 0xF, 0xF, true));
}

// Broadcast the 4 gate rows to all lanes (slot order probed at init).
__device__ __forceinline__ void gate_xchg(float act, int kp,
                                          float& s0, float& s1,
                                          float& s2, float& s3) {
#if __has_builtin(__builtin_amdgcn_permlane32_swap) && __has_builtin(__builtin_amdgcn_permlane16_swap)
    const unsigned a = __float_as_uint(act);
    const u32x2 pq = __builtin_amdgcn_permlane32_swap(a, a, false, false);
    const u32x2 rs = __builtin_amdgcn_permlane16_swap(pq.x, pq.x, false, false);
    const u32x2 tu = __builtin_amdgcn_permlane16_swap(pq.y, pq.y, false, false);
    s0 = __uint_as_float(rs.x); s1 = __uint_as_float(rs.y);
    s2 = __uint_as_float(tu.x); s3 = __uint_as_float(tu.y);
#else
    s0 = __shfl(act, kp,      64);
    s1 = __shfl(act, kp + 16, 64);
    s2 = __shfl(act, kp + 32, 64);
    s3 = __shfl(act, kp + 48, 64);
#endif
}

__global__ __launch_bounds__(64) void lstm_decoder_kernel(
    const float* __restrict__ y,     // (B,16)
    const float* __restrict__ u,     // (B,128)
    const float* __restrict__ W_ih,  // (64,1)
    const float* __restrict__ W_hh,  // (64,16)
    const float* __restrict__ b_ih,  // (64)
    const float* __restrict__ b_hh,  // (64)
    const float* __restrict__ W_lin, // (1,16)
    const float* __restrict__ b_lin, // (1)
    const float* __restrict__ W_h0,  // (16,128)
    const float* __restrict__ b_h0,  // (16)
    const float* __restrict__ W_c0,  // (16,128)
    const float* __restrict__ b_c0,  // (16)
    float* __restrict__ out)         // (B,144)
{
    const int b  = blockIdx.x;    // batch chain
    const int j  = threadIdx.x;   // lane 0..63
    const int kp = j & 15;        // hidden index this lane carries

    __shared__ float lds_u[R_];
    __shared__ float lds_h[H_];
    __shared__ float lds_c[H_];

    // ---- stage u[b,:] to LDS (coalesced) ----
    lds_u[j]      = u[b * R_ + j];
    lds_u[j + 64] = u[b * R_ + j + 64];
    __syncthreads();

    // ---- h0 / c0 init: lanes 0..15 -> h0[kp], lanes 16..31 -> c0[kp] ----
    if (j < 32) {
        const float* Wr = (j < 16) ? (W_h0 + kp * R_) : (W_c0 + kp * R_);
        float acc = (j < 16) ? b_h0[kp] : b_c0[kp];
        #pragma unroll
        for (int r = 0; r < R_; r += 4) {
            float4 wv = *(const float4*)(Wr + r);
            float4 uv = *(const float4*)(&lds_u[r]);
            acc = fmaf(wv.x, uv.x, acc);
            acc = fmaf(wv.y, uv.y, acc);
            acc = fmaf(wv.z, uv.z, acc);
            acc = fmaf(wv.w, uv.w, acc);
        }
        if (j < 16) lds_h[kp] = acc;
        else        lds_c[kp] = acc;
    }

    // ---- probe 1: DPP row_ror direction ----
    const int probe = __builtin_amdgcn_update_dpp(0, kp, 0x121, 0xF, 0xF, true);
    const bool plus = (probe == ((kp + 1) & 15));

    // ---- probe 2: gate-exchange slot->row mapping ----
    // Feed row-id through the network; slot m receives row pr_m. Relabel so
    // that THIS lane computes the gate whose slot will carry its row:
    //   slot 0 = i, slot 1 = f, slot 2 = g, slot 3 = o  (by construction).
    const float rowf = (float)(j >> 4);
    float pr0, pr1, pr2, pr3;
    gate_xchg(rowf, kp, pr0, pr1, pr2, pr3);
    const int m = (pr0 == rowf) ? 0 : (pr1 == rowf) ? 1 : (pr2 == rowf) ? 2 : 3;

    // ---- per-lane pre-scaled, pre-permuted weights for gate m of kp ----
    const float LOG2E = 1.4426950408889634f;
    const float cK    = -2.0f * LOG2E;           // tanh(c) exp2 scale
    const bool  isg   = (m == 2);
    const float sj    = isg ? (-2.0f * LOG2E) : (-LOG2E);
    const int   grow  = 16 * m + kp;             // row of W_hh for my gate
    float w16[H_], wlr[H_];
    #pragma unroll
    for (int r = 0; r < H_; ++r) {
        const int idx = plus ? ((kp + r) & 15) : ((kp - r) & 15);
        w16[r] = sj * W_hh[grow * H_ + idx];
        wlr[r] = W_lin[idx];
    }
    const float bj  = sj * (b_ih[grow] + b_hh[grow]);
    const float wij = sj * W_ih[grow];
    // act = fmaf(aAct, sigma, bAct):
    //   gate i (m==0): cK * sigma   (pre-scales iv -> c stays in cK domain)
    //   gates f,o:      1 * sigma
    //   gate g (m==2):  2 * sigma - 1 = tanh  (e = e^{-2z} via sj)
    const float aAct = isg ? 2.0f : ((m == 0) ? cK : 1.0f);
    const float bAct = isg ? -1.0f : 0.0f;
    const float bl   = b_lin[0];

    __syncthreads();
    float hk = lds_h[kp];          // h[kp], replicated across the 4 rows
    float c  = cK * lds_c[kp];     // c in SCALED domain: c' = cK * c_nat

    float win[A_];
    #pragma unroll
    for (int t = 0; t < A_; ++t) win[t] = y[b * A_ + t];

    float pout0 = 0.f, pout1 = 0.f;

    for (int s = 0; s < T_; ++s) {
        #pragma unroll
        for (int t = 0; t < A_; ++t) {
            const float x = win[t];
            // ---- own-gate dot via DPP row all-gather (no LDS) ----
            float z0 = fmaf(x, wij, bj);
            z0 = fmaf(hk, w16[0], z0);
            float z1, z2, z3;
            { const float hr = dpp_rotf<0x121>(hk); z1 = hr * w16[1]; }
            { const float hr = dpp_rotf<0x122>(hk); z2 = hr * w16[2]; }
            { const float hr = dpp_rotf<0x123>(hk); z3 = hr * w16[3]; }
#define CELL_ROT(R, CTRL, ACC)                                        \
            { const float hr = dpp_rotf<CTRL>(hk);                    \
              ACC = fmaf(hr, w16[R], ACC); }
            CELL_ROT(4,  0x124, z0)
            CELL_ROT(5,  0x125, z1)
            CELL_ROT(6,  0x126, z2)
            CELL_ROT(7,  0x127, z3)
            CELL_ROT(8,  0x128, z0)
            CELL_ROT(9,  0x129, z1)
            CELL_ROT(10, 0x12A, z2)
            CELL_ROT(11, 0x12B, z3)
            CELL_ROT(12, 0x12C, z0)
            CELL_ROT(13, 0x12D, z1)
            CELL_ROT(14, 0x12E, z2)
            CELL_ROT(15, 0x12F, z3)
#undef CELL_ROT
            const float z = (z0 + z1) + (z2 + z3);

            // ---- own-gate activation ----
            const float e   = __builtin_amdgcn_exp2f(z);
            const float sg  = __builtin_amdgcn_rcpf(1.0f + e);
            const float act = fmaf(aAct, sg, bAct);

            // ---- gate exchange: 3 cross-row VALU permutes (no LDS) ----
            float iv, fv, gg, ov;
            gate_xchg(act, kp, iv, fv, gg, ov);

            // ---- c (scaled domain), tanh(c), h[kp] ----
            c = fmaf(fv, c, iv * gg);                    // c' = cK * c_nat
            const float ec = __builtin_amdgcn_exp2f(c);  // e^{-2 c_nat}
            const float rc = __builtin_amdgcn_rcpf(1.0f + ec);
            const float nm = fmaf(-ov, ec, ov);          // ov*(1-ec)
            hk = nm * rc;                                // ov*tanh(c_nat)
        }

        // ---- pred = h . W_lin + b_lin via one more DPP all-gather ----
        float pa = fmaf(hk, wlr[0], bl);
        float pb;
        { const float hr = dpp_rotf<0x121>(hk); pb = hr * wlr[1]; }
#define PRED_ROT(R, CTRL, ACC)                                        \
        { const float hr = dpp_rotf<CTRL>(hk);                        \
          ACC = fmaf(hr, wlr[R], ACC); }
        PRED_ROT(2,  0x122, pa)
        PRED_ROT(3,  0x123, pb)
        PRED_ROT(4,  0x124, pa)
        PRED_ROT(5,  0x125, pb)
        PRED_ROT(6,  0x126, pa)
        PRED_ROT(7,  0x127, pb)
        PRED_ROT(8,  0x128, pa)
        PRED_ROT(9,  0x129, pb)
        PRED_ROT(10, 0x12A, pa)
        PRED_ROT(11, 0x12B, pb)
        PRED_ROT(12, 0x12C, pa)
        PRED_ROT(13, 0x12D, pb)
        PRED_ROT(14, 0x12E, pa)
        PRED_ROT(15, 0x12F, pb)
#undef PRED_ROT
        const float p = pa + pb;

        // ---- window slide + pred stash ----
        #pragma unroll
        for (int t = 0; t < A_ - 1; ++t) win[t] = win[t + 1];
        win[A_ - 1] = p;
        if (s == j)      pout0 = p;
        if (s == j + 64) pout1 = p;
    }

    // ---- output: out[b,0:16]=y[b,:], out[b,16+s]=pred_s ----
    if (j < A_) out[b * (A_ + T_) + j] = y[b * A_ + j];
    out[b * (A_ + T_) + A_ + j]      = pout0;
    out[b * (A_ + T_) + A_ + 64 + j] = pout1;
}

extern "C" void kernel_launch(void* const* d_in, const int* in_sizes, int n_in,
                              void* d_out, int out_size, void* d_ws, size_t ws_size,
                              hipStream_t stream) {
    const float* y     = (const float*)d_in[0];
    const float* u     = (const float*)d_in[1];
    const float* W_ih  = (const float*)d_in[2];
    const float* W_hh  = (const float*)d_in[3];
    const float* b_ih  = (const float*)d_in[4];
    const float* b_hh  = (const float*)d_in[5];
    const float* W_lin = (const float*)d_in[6];
    const float* b_lin = (const float*)d_in[7];
    const float* W_h0  = (const float*)d_in[8];
    const float* b_h0  = (const float*)d_in[9];
    const float* W_c0  = (const float*)d_in[10];
    const float* b_c0  = (const float*)d_in[11];
    float* out = (float*)d_out;

    lstm_decoder_kernel<<<B_, 64, 0, stream>>>(
        y, u, W_ih, W_hh, b_ih, b_hh, W_lin, b_lin,
        W_h0, b_h0, W_c0, b_c0, out);
}

// Round 14
// 278.277 us; speedup vs baseline: 1.3885x; 1.1340x over previous
//
#include <hip/hip_runtime.h>

// LSTM decoder: B=1024, H=16, 4H=64 gates, T=128 steps x 16 cells = 2048
// strictly-serial cell evaluations per batch chain.
//
// Round-14 = round-13 (263us kernel = 308 cyc/cell: 242 busy + 66 exposed)
// with the h all-gather's 15 v_mov_b32_dpp FUSED into the MACs via inline
// asm v_mul_f32_dpp / v_fmac_f32_dpp (VOP2+DPP; VOP3 v_fma can't take DPP,
// which is why the movs existed). Bit-identical math, -15 inst/cell.
// DPP hazard (VALU write -> cross-lane read needs 2 wait states) covered by
// s_nop 1 at the asm block head plus >=2 intervening deps in practice.
//
// Carried structure: one wave per chain; lane computes one gate (relabeled
// by the probed permlane slot mapping); 3 permlane16/32_swap VALU ops do
// the i/f/g/o exchange (no LDS in the hot loop at all); c kept in the
// exp2-scaled domain (cK folded into the i-gate activation constant);
// tail tanh = fmaf(-ov,ec,ov)*rcp(1+ec).

#define B_ 1024
#define A_ 16
#define T_ 128
#define R_ 128
#define H_ 16

typedef unsigned int u32x2 __attribute__((ext_vector_type(2)));

template<int CTRL>
__device__ __forceinline__ float dpp_rotf(float v) {
    return __int_as_float(__builtin_amdgcn_update_dpp(
        0, __float_as_int(v), CTRL, 0xF, 0xF, true));
}

// Broadcast the 4 gate rows to all lanes (slot order probed at init).
__device__ __forceinline__ void gate_xchg(float act, int kp,
                                          float& s0, float& s1,
                                          float& s2, float& s3) {
#if __has_builtin(__builtin_amdgcn_permlane32_swap) && __has_builtin(__builtin_amdgcn_permlane16_swap)
    const unsigned a = __float_as_uint(act);
    const u32x2 pq = __builtin_amdgcn_permlane32_swap(a, a, false, false);
    const u32x2 rs = __builtin_amdgcn_permlane16_swap(pq.x, pq.x, false, false);
    const u32x2 tu = __builtin_amdgcn_permlane16_swap(pq.y, pq.y, false, false);
    s0 = __uint_as_float(rs.x); s1 = __uint_as_float(rs.y);
    s2 = __uint_as_float(tu.x); s3 = __uint_as_float(tu.y);
#else
    s0 = __shfl(act, kp,      64);
    s1 = __shfl(act, kp + 16, 64);
    s2 = __shfl(act, kp + 32, 64);
    s3 = __shfl(act, kp + 48, 64);
#endif
}

__global__ __launch_bounds__(64) void lstm_decoder_kernel(
    const float* __restrict__ y,     // (B,16)
    const float* __restrict__ u,     // (B,128)
    const float* __restrict__ W_ih,  // (64,1)
    const float* __restrict__ W_hh,  // (64,16)
    const float* __restrict__ b_ih,  // (64)
    const float* __restrict__ b_hh,  // (64)
    const float* __restrict__ W_lin, // (1,16)
    const float* __restrict__ b_lin, // (1)
    const float* __restrict__ W_h0,  // (16,128)
    const float* __restrict__ b_h0,  // (16)
    const float* __restrict__ W_c0,  // (16,128)
    const float* __restrict__ b_c0,  // (16)
    float* __restrict__ out)         // (B,144)
{
    const int b  = blockIdx.x;    // batch chain
    const int j  = threadIdx.x;   // lane 0..63
    const int kp = j & 15;        // hidden index this lane carries

    __shared__ float lds_u[R_];
    __shared__ float lds_h[H_];
    __shared__ float lds_c[H_];

    // ---- stage u[b,:] to LDS (coalesced) ----
    lds_u[j]      = u[b * R_ + j];
    lds_u[j + 64] = u[b * R_ + j + 64];
    __syncthreads();

    // ---- h0 / c0 init: lanes 0..15 -> h0[kp], lanes 16..31 -> c0[kp] ----
    if (j < 32) {
        const float* Wr = (j < 16) ? (W_h0 + kp * R_) : (W_c0 + kp * R_);
        float acc = (j < 16) ? b_h0[kp] : b_c0[kp];
        #pragma unroll
        for (int r = 0; r < R_; r += 4) {
            float4 wv = *(const float4*)(Wr + r);
            float4 uv = *(const float4*)(&lds_u[r]);
            acc = fmaf(wv.x, uv.x, acc);
            acc = fmaf(wv.y, uv.y, acc);
            acc = fmaf(wv.z, uv.z, acc);
            acc = fmaf(wv.w, uv.w, acc);
        }
        if (j < 16) lds_h[kp] = acc;
        else        lds_c[kp] = acc;
    }

    // ---- probe 1: DPP row_ror direction ----
    const int probe = __builtin_amdgcn_update_dpp(0, kp, 0x121, 0xF, 0xF, true);
    const bool plus = (probe == ((kp + 1) & 15));

    // ---- probe 2: gate-exchange slot->row mapping; relabel this lane ----
    const float rowf = (float)(j >> 4);
    float pr0, pr1, pr2, pr3;
    gate_xchg(rowf, kp, pr0, pr1, pr2, pr3);
    const int m = (pr0 == rowf) ? 0 : (pr1 == rowf) ? 1 : (pr2 == rowf) ? 2 : 3;

    // ---- per-lane pre-scaled, pre-permuted weights for gate m of kp ----
    const float LOG2E = 1.4426950408889634f;
    const float cK    = -2.0f * LOG2E;           // tanh(c) exp2 scale
    const bool  isg   = (m == 2);
    const float sj    = isg ? (-2.0f * LOG2E) : (-LOG2E);
    const int   grow  = 16 * m + kp;             // row of W_hh for my gate
    float w16[H_], wlr[H_];
    #pragma unroll
    for (int r = 0; r < H_; ++r) {
        const int idx = plus ? ((kp + r) & 15) : ((kp - r) & 15);
        w16[r] = sj * W_hh[grow * H_ + idx];
        wlr[r] = W_lin[idx];
    }
    const float bj  = sj * (b_ih[grow] + b_hh[grow]);
    const float wij = sj * W_ih[grow];
    const float aAct = isg ? 2.0f : ((m == 0) ? cK : 1.0f);
    const float bAct = isg ? -1.0f : 0.0f;
    const float bl   = b_lin[0];

    __syncthreads();
    float hk = lds_h[kp];          // h[kp], replicated across the 4 rows
    float c  = cK * lds_c[kp];     // c in SCALED domain: c' = cK * c_nat

    float win[A_];
    #pragma unroll
    for (int t = 0; t < A_; ++t) win[t] = y[b * A_ + t];

    float pout0 = 0.f, pout1 = 0.f;

    for (int s = 0; s < T_; ++s) {
        #pragma unroll
        for (int t = 0; t < A_; ++t) {
            const float x = win[t];
            // ---- own-gate dot; gather FUSED into MACs (VOP2+DPP) ----
            float z0 = fmaf(x, wij, bj);
            z0 = fmaf(hk, w16[0], z0);
            float z1, z2, z3;
            asm("s_nop 1\n\t"
                "v_mul_f32_dpp  %1, %4, %6  row_ror:1  row_mask:0xf bank_mask:0xf\n\t"
                "v_mul_f32_dpp  %2, %4, %7  row_ror:2  row_mask:0xf bank_mask:0xf\n\t"
                "v_mul_f32_dpp  %3, %4, %8  row_ror:3  row_mask:0xf bank_mask:0xf\n\t"
                "v_fmac_f32_dpp %0, %4, %9  row_ror:4  row_mask:0xf bank_mask:0xf\n\t"
                "v_fmac_f32_dpp %1, %4, %10 row_ror:5  row_mask:0xf bank_mask:0xf\n\t"
                "v_fmac_f32_dpp %2, %4, %11 row_ror:6  row_mask:0xf bank_mask:0xf\n\t"
                "v_fmac_f32_dpp %3, %4, %12 row_ror:7  row_mask:0xf bank_mask:0xf\n\t"
                "v_fmac_f32_dpp %0, %4, %13 row_ror:8  row_mask:0xf bank_mask:0xf\n\t"
                "v_fmac_f32_dpp %1, %4, %14 row_ror:9  row_mask:0xf bank_mask:0xf\n\t"
                "v_fmac_f32_dpp %2, %4, %15 row_ror:10 row_mask:0xf bank_mask:0xf\n\t"
                "v_fmac_f32_dpp %3, %4, %16 row_ror:11 row_mask:0xf bank_mask:0xf\n\t"
                "v_fmac_f32_dpp %0, %4, %17 row_ror:12 row_mask:0xf bank_mask:0xf\n\t"
                "v_fmac_f32_dpp %1, %4, %18 row_ror:13 row_mask:0xf bank_mask:0xf\n\t"
                "v_fmac_f32_dpp %2, %4, %19 row_ror:14 row_mask:0xf bank_mask:0xf\n\t"
                "v_fmac_f32_dpp %3, %4, %20 row_ror:15 row_mask:0xf bank_mask:0xf"
                : "+v"(z0), "=&v"(z1), "=&v"(z2), "=&v"(z3)
                : "v"(hk),
                  "v"(w16[0]),  "v"(w16[1]),  "v"(w16[2]),  "v"(w16[3]),
                  "v"(w16[4]),  "v"(w16[5]),  "v"(w16[6]),  "v"(w16[7]),
                  "v"(w16[8]),  "v"(w16[9]),  "v"(w16[10]), "v"(w16[11]),
                  "v"(w16[12]), "v"(w16[13]), "v"(w16[14]), "v"(w16[15]));
            const float z = (z0 + z1) + (z2 + z3);

            // ---- own-gate activation ----
            const float e   = __builtin_amdgcn_exp2f(z);
            const float sg  = __builtin_amdgcn_rcpf(1.0f + e);
            const float act = fmaf(aAct, sg, bAct);

            // ---- gate exchange: 3 cross-row VALU permutes (no LDS) ----
            float iv, fv, gg, ov;
            gate_xchg(act, kp, iv, fv, gg, ov);

            // ---- c (scaled domain), tanh(c), h[kp] ----
            c = fmaf(fv, c, iv * gg);                    // c' = cK * c_nat
            const float ec = __builtin_amdgcn_exp2f(c);  // e^{-2 c_nat}
            const float rc = __builtin_amdgcn_rcpf(1.0f + ec);
            const float nm = fmaf(-ov, ec, ov);          // ov*(1-ec)
            hk = nm * rc;                                // ov*tanh(c_nat)
        }

        // ---- pred = h . W_lin + b_lin via DPP all-gather (builtin movs;
        //      runs once per 16 cells, not worth asm risk) ----
        float pa = fmaf(hk, wlr[0], bl);
        float pb;
        { const float hr = dpp_rotf<0x121>(hk); pb = hr * wlr[1]; }
#define PRED_ROT(R, CTRL, ACC)                                        \
        { const float hr = dpp_rotf<CTRL>(hk);                        \
          ACC = fmaf(hr, wlr[R], ACC); }
        PRED_ROT(2,  0x122, pa)
        PRED_ROT(3,  0x123, pb)
        PRED_ROT(4,  0x124, pa)
        PRED_ROT(5,  0x125, pb)
        PRED_ROT(6,  0x126, pa)
        PRED_ROT(7,  0x127, pb)
        PRED_ROT(8,  0x128, pa)
        PRED_ROT(9,  0x129, pb)
        PRED_ROT(10, 0x12A, pa)
        PRED_ROT(11, 0x12B, pb)
        PRED_ROT(12, 0x12C, pa)
        PRED_ROT(13, 0x12D, pb)
        PRED_ROT(14, 0x12E, pa)
        PRED_ROT(15, 0x12F, pb)
#undef PRED_ROT
        const float p = pa + pb;

        // ---- window slide + pred stash ----
        #pragma unroll
        for (int t = 0; t < A_ - 1; ++t) win[t] = win[t + 1];
        win[A_ - 1] = p;
        if (s == j)      pout0 = p;
        if (s == j + 64) pout1 = p;
    }

    // ---- output: out[b,0:16]=y[b,:], out[b,16+s]=pred_s ----
    if (j < A_) out[b * (A_ + T_) + j] = y[b * A_ + j];
    out[b * (A_ + T_) + A_ + j]      = pout0;
    out[b * (A_ + T_) + A_ + 64 + j] = pout1;
}

extern "C" void kernel_launch(void* const* d_in, const int* in_sizes, int n_in,
                              void* d_out, int out_size, void* d_ws, size_t ws_size,
                              hipStream_t stream) {
    const float* y     = (const float*)d_in[0];
    const float* u     = (const float*)d_in[1];
    const float* W_ih  = (const float*)d_in[2];
    const float* W_hh  = (const float*)d_in[3];
    const float* b_ih  = (const float*)d_in[4];
    const float* b_hh  = (const float*)d_in[5];
    const float* W_lin = (const float*)d_in[6];
    const float* b_lin = (const float*)d_in[7];
    const float* W_h0  = (const float*)d_in[8];
    const float* b_h0  = (const float*)d_in[9];
    const float* W_c0  = (const float*)d_in[10];
    const float* b_c0  = (const float*)d_in[11];
    float* out = (float*)d_out;

    lstm_decoder_kernel<<<B_, 64, 0, stream>>>(
        y, u, W_ih, W_hh, b_ih, b_hh, W_lin, b_lin,
        W_h0, b_h0, W_c0, b_c0, out);
}

// Round 15
// 271.414 us; speedup vs baseline: 1.4236x; 1.0253x over previous
//
#include <hip/hip_runtime.h>

// LSTM decoder: B=1024, H=16, 4H=64 gates, T=128 steps x 16 cells = 2048
// strictly-serial cell evaluations per batch chain.
//
// Round-15 = round-14 (222us kernel = 260 cyc/cell: 193 busy + 67 exposed)
// with two amortized-cost cuts:
//  1. pred = h.W_lin + b_lin computed as a DPP ROW-SUM REDUCTION (it is a
//     broadcast reduction, unlike the gate dot): pm = hk*W_lin[kp], then
//     4 x v_add_f32_dpp row_ror 8/4/2/1 -> every lane holds the full sum.
//     5 asm insts + hazard nops vs the old 33-inst gather (15 dpp movs +
//     16 fma). Also deletes the 16-reg wlr[] permuted array.
//  2. s-loop unrolled x2 (loop overhead ~3 cyc/cell).
//
// Carried: per-lane one-gate mapping relabeled by probed permlane slots;
// 15 v_mul/v_fmac_f32_dpp fused gather-MACs (asm); 3 permlane16/32_swap
// gate exchange; c in exp2-scaled domain; tanh tail fmaf(-ov,ec,ov)*rcp.

#define B_ 1024
#define A_ 16
#define T_ 128
#define R_ 128
#define H_ 16

typedef unsigned int u32x2 __attribute__((ext_vector_type(2)));

template<int CTRL>
__device__ __forceinline__ float dpp_rotf(float v) {
    return __int_as_float(__builtin_amdgcn_update_dpp(
        0, __float_as_int(v), CTRL, 0xF, 0xF, true));
}

// Broadcast the 4 gate rows to all lanes (slot order probed at init).
__device__ __forceinline__ void gate_xchg(float act, int kp,
                                          float& s0, float& s1,
                                          float& s2, float& s3) {
#if __has_builtin(__builtin_amdgcn_permlane32_swap) && __has_builtin(__builtin_amdgcn_permlane16_swap)
    const unsigned a = __float_as_uint(act);
    const u32x2 pq = __builtin_amdgcn_permlane32_swap(a, a, false, false);
    const u32x2 rs = __builtin_amdgcn_permlane16_swap(pq.x, pq.x, false, false);
    const u32x2 tu = __builtin_amdgcn_permlane16_swap(pq.y, pq.y, false, false);
    s0 = __uint_as_float(rs.x); s1 = __uint_as_float(rs.y);
    s2 = __uint_as_float(tu.x); s3 = __uint_as_float(tu.y);
#else
    s0 = __shfl(act, kp,      64);
    s1 = __shfl(act, kp + 16, 64);
    s2 = __shfl(act, kp + 32, 64);
    s3 = __shfl(act, kp + 48, 64);
#endif
}

// Row-wide sum via DPP rotations: every lane ends with sum over its 16-lane
// row. Direction-agnostic (any consistent rotation gives a complete tree).
__device__ __forceinline__ float row_sum(float m) {
    float pm = m;
    asm("s_nop 1\n\t"
        "v_add_f32_dpp %0, %0, %0 row_ror:8 row_mask:0xf bank_mask:0xf\n\t"
        "s_nop 1\n\t"
        "v_add_f32_dpp %0, %0, %0 row_ror:4 row_mask:0xf bank_mask:0xf\n\t"
        "s_nop 1\n\t"
        "v_add_f32_dpp %0, %0, %0 row_ror:2 row_mask:0xf bank_mask:0xf\n\t"
        "s_nop 1\n\t"
        "v_add_f32_dpp %0, %0, %0 row_ror:1 row_mask:0xf bank_mask:0xf"
        : "+v"(pm));
    return pm;
}

__global__ __launch_bounds__(64) void lstm_decoder_kernel(
    const float* __restrict__ y,     // (B,16)
    const float* __restrict__ u,     // (B,128)
    const float* __restrict__ W_ih,  // (64,1)
    const float* __restrict__ W_hh,  // (64,16)
    const float* __restrict__ b_ih,  // (64)
    const float* __restrict__ b_hh,  // (64)
    const float* __restrict__ W_lin, // (1,16)
    const float* __restrict__ b_lin, // (1)
    const float* __restrict__ W_h0,  // (16,128)
    const float* __restrict__ b_h0,  // (16)
    const float* __restrict__ W_c0,  // (16,128)
    const float* __restrict__ b_c0,  // (16)
    float* __restrict__ out)         // (B,144)
{
    const int b  = blockIdx.x;    // batch chain
    const int j  = threadIdx.x;   // lane 0..63
    const int kp = j & 15;        // hidden index this lane carries

    __shared__ float lds_u[R_];
    __shared__ float lds_h[H_];
    __shared__ float lds_c[H_];

    // ---- stage u[b,:] to LDS (coalesced) ----
    lds_u[j]      = u[b * R_ + j];
    lds_u[j + 64] = u[b * R_ + j + 64];
    __syncthreads();

    // ---- h0 / c0 init: lanes 0..15 -> h0[kp], lanes 16..31 -> c0[kp] ----
    if (j < 32) {
        const float* Wr = (j < 16) ? (W_h0 + kp * R_) : (W_c0 + kp * R_);
        float acc = (j < 16) ? b_h0[kp] : b_c0[kp];
        #pragma unroll
        for (int r = 0; r < R_; r += 4) {
            float4 wv = *(const float4*)(Wr + r);
            float4 uv = *(const float4*)(&lds_u[r]);
            acc = fmaf(wv.x, uv.x, acc);
            acc = fmaf(wv.y, uv.y, acc);
            acc = fmaf(wv.z, uv.z, acc);
            acc = fmaf(wv.w, uv.w, acc);
        }
        if (j < 16) lds_h[kp] = acc;
        else        lds_c[kp] = acc;
    }

    // ---- probe 1: DPP row_ror direction ----
    const int probe = __builtin_amdgcn_update_dpp(0, kp, 0x121, 0xF, 0xF, true);
    const bool plus = (probe == ((kp + 1) & 15));

    // ---- probe 2: gate-exchange slot->row mapping; relabel this lane ----
    const float rowf = (float)(j >> 4);
    float pr0, pr1, pr2, pr3;
    gate_xchg(rowf, kp, pr0, pr1, pr2, pr3);
    const int m = (pr0 == rowf) ? 0 : (pr1 == rowf) ? 1 : (pr2 == rowf) ? 2 : 3;

    // ---- per-lane pre-scaled, pre-permuted weights for gate m of kp ----
    const float LOG2E = 1.4426950408889634f;
    const float cK    = -2.0f * LOG2E;           // tanh(c) exp2 scale
    const bool  isg   = (m == 2);
    const float sj    = isg ? (-2.0f * LOG2E) : (-LOG2E);
    const int   grow  = 16 * m + kp;             // row of W_hh for my gate
    float w16[H_];
    #pragma unroll
    for (int r = 0; r < H_; ++r) {
        const int idx = plus ? ((kp + r) & 15) : ((kp - r) & 15);
        w16[r] = sj * W_hh[grow * H_ + idx];
    }
    const float bj  = sj * (b_ih[grow] + b_hh[grow]);
    const float wij = sj * W_ih[grow];
    const float aAct = isg ? 2.0f : ((m == 0) ? cK : 1.0f);
    const float bAct = isg ? -1.0f : 0.0f;
    const float wlk  = W_lin[kp];                // own-lane W_lin element
    const float bl   = b_lin[0];

    __syncthreads();
    float hk = lds_h[kp];          // h[kp], replicated across the 4 rows
    float c  = cK * lds_c[kp];     // c in SCALED domain: c' = cK * c_nat

    float win[A_];
    #pragma unroll
    for (int t = 0; t < A_; ++t) win[t] = y[b * A_ + t];

    float pout0 = 0.f, pout1 = 0.f;

    #pragma unroll 2
    for (int s = 0; s < T_; ++s) {
        #pragma unroll
        for (int t = 0; t < A_; ++t) {
            const float x = win[t];
            // ---- own-gate dot; gather FUSED into MACs (VOP2+DPP) ----
            float z0 = fmaf(x, wij, bj);
            z0 = fmaf(hk, w16[0], z0);
            float z1, z2, z3;
            asm("s_nop 1\n\t"
                "v_mul_f32_dpp  %1, %4, %6  row_ror:1  row_mask:0xf bank_mask:0xf\n\t"
                "v_mul_f32_dpp  %2, %4, %7  row_ror:2  row_mask:0xf bank_mask:0xf\n\t"
                "v_mul_f32_dpp  %3, %4, %8  row_ror:3  row_mask:0xf bank_mask:0xf\n\t"
                "v_fmac_f32_dpp %0, %4, %9  row_ror:4  row_mask:0xf bank_mask:0xf\n\t"
                "v_fmac_f32_dpp %1, %4, %10 row_ror:5  row_mask:0xf bank_mask:0xf\n\t"
                "v_fmac_f32_dpp %2, %4, %11 row_ror:6  row_mask:0xf bank_mask:0xf\n\t"
                "v_fmac_f32_dpp %3, %4, %12 row_ror:7  row_mask:0xf bank_mask:0xf\n\t"
                "v_fmac_f32_dpp %0, %4, %13 row_ror:8  row_mask:0xf bank_mask:0xf\n\t"
                "v_fmac_f32_dpp %1, %4, %14 row_ror:9  row_mask:0xf bank_mask:0xf\n\t"
                "v_fmac_f32_dpp %2, %4, %15 row_ror:10 row_mask:0xf bank_mask:0xf\n\t"
                "v_fmac_f32_dpp %3, %4, %16 row_ror:11 row_mask:0xf bank_mask:0xf\n\t"
                "v_fmac_f32_dpp %0, %4, %17 row_ror:12 row_mask:0xf bank_mask:0xf\n\t"
                "v_fmac_f32_dpp %1, %4, %18 row_ror:13 row_mask:0xf bank_mask:0xf\n\t"
                "v_fmac_f32_dpp %2, %4, %19 row_ror:14 row_mask:0xf bank_mask:0xf\n\t"
                "v_fmac_f32_dpp %3, %4, %20 row_ror:15 row_mask:0xf bank_mask:0xf"
                : "+v"(z0), "=&v"(z1), "=&v"(z2), "=&v"(z3)
                : "v"(hk),
                  "v"(w16[0]),  "v"(w16[1]),  "v"(w16[2]),  "v"(w16[3]),
                  "v"(w16[4]),  "v"(w16[5]),  "v"(w16[6]),  "v"(w16[7]),
                  "v"(w16[8]),  "v"(w16[9]),  "v"(w16[10]), "v"(w16[11]),
                  "v"(w16[12]), "v"(w16[13]), "v"(w16[14]), "v"(w16[15]));
            const float z = (z0 + z1) + (z2 + z3);

            // ---- own-gate activation ----
            const float e   = __builtin_amdgcn_exp2f(z);
            const float sg  = __builtin_amdgcn_rcpf(1.0f + e);
            const float act = fmaf(aAct, sg, bAct);

            // ---- gate exchange: 3 cross-row VALU permutes (no LDS) ----
            float iv, fv, gg, ov;
            gate_xchg(act, kp, iv, fv, gg, ov);

            // ---- c (scaled domain), tanh(c), h[kp] ----
            c = fmaf(fv, c, iv * gg);                    // c' = cK * c_nat
            const float ec = __builtin_amdgcn_exp2f(c);  // e^{-2 c_nat}
            const float rc = __builtin_amdgcn_rcpf(1.0f + ec);
            const float nm = fmaf(-ov, ec, ov);          // ov*(1-ec)
            hk = nm * rc;                                // ov*tanh(c_nat)
        }

        // ---- pred = h . W_lin + b_lin via 4-stage DPP row-sum ----
        const float p = row_sum(hk * wlk) + bl;

        // ---- window slide + pred stash ----
        #pragma unroll
        for (int t = 0; t < A_ - 1; ++t) win[t] = win[t + 1];
        win[A_ - 1] = p;
        if (s == j)      pout0 = p;
        if (s == j + 64) pout1 = p;
    }

    // ---- output: out[b,0:16]=y[b,:], out[b,16+s]=pred_s ----
    if (j < A_) out[b * (A_ + T_) + j] = y[b * A_ + j];
    out[b * (A_ + T_) + A_ + j]      = pout0;
    out[b * (A_ + T_) + A_ + 64 + j] = pout1;
}

extern "C" void kernel_launch(void* const* d_in, const int* in_sizes, int n_in,
                              void* d_out, int out_size, void* d_ws, size_t ws_size,
                              hipStream_t stream) {
    const float* y     = (const float*)d_in[0];
    const float* u     = (const float*)d_in[1];
    const float* W_ih  = (const float*)d_in[2];
    const float* W_hh  = (const float*)d_in[3];
    const float* b_ih  = (const float*)d_in[4];
    const float* b_hh  = (const float*)d_in[5];
    const float* W_lin = (const float*)d_in[6];
    const float* b_lin = (const float*)d_in[7];
    const float* W_h0  = (const float*)d_in[8];
    const float* b_h0  = (const float*)d_in[9];
    const float* W_c0  = (const float*)d_in[10];
    const float* b_c0  = (const float*)d_in[11];
    float* out = (float*)d_out;

    lstm_decoder_kernel<<<B_, 64, 0, stream>>>(
        y, u, W_ih, W_hh, b_ih, b_hh, W_lin, b_lin,
        W_h0, b_h0, W_c0, b_c0, out);
}